// Round 6
// baseline (2150.955 us; speedup 1.0000x reference)
//
#include <hip/hip_runtime.h>

#define DEV __device__ __forceinline__

typedef __attribute__((ext_vector_type(8))) short short8;
typedef __attribute__((ext_vector_type(4))) float floatx4;
typedef __attribute__((ext_vector_type(4))) int   intx4;
typedef __attribute__((ext_vector_type(2))) int   intx2;
typedef unsigned long long ull;

static constexpr int B_ = 512, T_ = 912, H_ = 128, F_ = 32;
static constexpr size_t HN_OFF   = 1024;                       // bf16 hN[4][512][128]
static constexpr size_t XT_OFF   = HN_OFF + (size_t)4 * 512 * 128 * 2;   // 525312
static constexpr size_t RING_OFF = XT_OFF + (size_t)T_ * B_ * F_ * 2;    // 30409728
// ring per boundary-group: 8 chunk-regions x 32KB ([8 slots][16 rows][256B])
static constexpr size_t RING_BPG = 8 * 32768;                  // 256 KB

template <int N> struct IC { static constexpr int value = N; };

DEV unsigned short bf16rne(float f) {
    unsigned u = __builtin_bit_cast(unsigned, f);
    u += 0x7FFFu + ((u >> 16) & 1u);
    return (unsigned short)(u >> 16);
}
DEV float bf16tof(unsigned short u) {
    return __builtin_bit_cast(float, ((unsigned)u) << 16);
}
DEV float fastsig(float y) {     // rcp(1+exp2(y))
    return __builtin_amdgcn_rcpf(1.f + __builtin_amdgcn_exp2f(y));
}
DEV float sigm(float x) { return fastsig(-1.44269504f * x); }
DEV unsigned ald(const unsigned* p) {
    return __hip_atomic_load(p, __ATOMIC_RELAXED, __HIP_MEMORY_SCOPE_AGENT);
}
DEV void ast32(unsigned* p, unsigned v) {
    __hip_atomic_store(p, v, __ATOMIC_RELAXED, __HIP_MEMORY_SCOPE_AGENT);
}
DEV void bar_fast() {            // LDS-only barrier: no vmcnt drain
    asm volatile("s_waitcnt lgkmcnt(0)\n\ts_barrier" ::: "memory");
}
// 16B device-scope (sc0 sc1) ring accesses — plain path, not atomic path.
DEV void st16_sc1(void* p, intx4 v) {
    asm volatile("global_store_dwordx4 %0, %1, off sc0 sc1"
                 :: "v"(p), "v"(v) : "memory");
}
DEV void ld16_sc1_issue(const void* p, intx4* v) {   // issue only — NO wait
    asm volatile("global_load_dwordx4 %0, %1, off sc0 sc1"
                 : "=v"(*v) : "v"(p) : "memory");
}
DEV void wait_vm0() {
    asm volatile("s_waitcnt vmcnt(0)" ::: "memory");
}
DEV void wait_vm0_tied(intx4* a, intx4* b, intx4* c, intx4* d) {
    asm volatile("s_waitcnt vmcnt(0)"
                 : "+v"(*a), "+v"(*b), "+v"(*c), "+v"(*d) :: "memory");
}

// ---------------------------------------------------------------------------
// x [B][T][32] fp32  ->  xT [T][B][32] bf16
__global__ __launch_bounds__(256) void xpose(const float* __restrict__ x,
                                             unsigned short* __restrict__ xT) {
    int tid = blockIdx.x * 256 + threadIdx.x;
    if (tid >= B_ * T_ * 4) return;
    int k = tid & 3;
    int r = tid >> 2;                                  // r = b*912 + t
    int b = r / T_;
    int t = r - b * T_;
    const float* p = x + ((size_t)r * 32 + k * 8);
    short8 v;
#pragma unroll
    for (int j = 0; j < 8; j++) v[j] = (short)bf16rne(p[j]);
    *(short8*)(xT + ((size_t)t * 512 + b) * 32 + k * 8) = v;
}

// ---------------------------------------------------------------------------
// Pipelined 4-layer LSTM scan. 128 blocks = 4 layers x 32 groups (16 samples).
// R6: ring handoff uses 16B plain sc0+sc1 loads/stores (inline asm) instead of
// 8B agent atomics — half the transactions, cacheable path. Release ordering:
// explicit s_waitcnt vmcnt(0) before the per-chunk __syncthreads + flag store.
__global__ __launch_bounds__(512, 2) void lstm_scan(
    const float* __restrict__ Wih0, const float* __restrict__ Whh0,
    const float* __restrict__ bih0, const float* __restrict__ bhh0,
    const float* __restrict__ Wih123, const float* __restrict__ Whh123,
    const float* __restrict__ bih123, const float* __restrict__ bhh123,
    char* __restrict__ ws) {
    const int tid  = threadIdx.x;
    const int wv   = tid >> 6;
    const int lane = tid & 63;
    const int col  = lane & 15;
    const int quad = lane >> 4;
    const int layer = blockIdx.x >> 5;
    const int grp   = blockIdx.x & 31;
    const int b0    = grp * 16;

    unsigned* flags = (unsigned*)ws;                   // [4][32] chunks published
    unsigned* cons  = (unsigned*)(ws + 512);           // [4][32] chunks loaded
    char* hN8 = ws + HN_OFF;
    const char* xTB = ws + XT_OFF;

    __shared__ unsigned short Ah[16][16][132];         // h history ring (slot = t&15)
    __shared__ unsigned short Xl[16][16][132];         // staged input (slot = t&15)
    char* AhB = (char*)Ah;
    char* XlB = (char*)Xl;

    for (int i = tid; i < 16 * 16 * 132; i += 512) {
        ((unsigned short*)Ah)[i] = 0;
        ((unsigned short*)Xl)[i] = 0;
    }

    // ---- persistent weights, activation scale folded in ------------------
    short8 wh[4][4];
    short8 wx[4][4];
    float  bias_q[4];
    {
        const float *Wih, *Whh, *bih, *bhh;
        int kin, KX;
        if (layer == 0) { Wih = Wih0; Whh = Whh0; bih = bih0; bhh = bhh0; kin = 32; KX = 1; }
        else {
            Wih = Wih123 + (size_t)(layer - 1) * 512 * 128;
            Whh = Whh123 + (size_t)(layer - 1) * 512 * 128;
            bih = bih123 + (size_t)(layer - 1) * 512;
            bhh = bhh123 + (size_t)(layer - 1) * 512;
            kin = 128; KX = 4;
        }
#pragma unroll
        for (int q = 0; q < 4; q++) {
            const float sc = (q == 2) ? -2.88539008f : -1.44269504f;
            int row = q * 128 + wv * 16 + col;
            bias_q[q] = (bih[row] + bhh[row]) * sc;
#pragma unroll
            for (int kt = 0; kt < 4; kt++) {
                const float* ph = Whh + (size_t)row * 128 + kt * 32 + quad * 8;
                short8 v;
#pragma unroll
                for (int j = 0; j < 8; j++) v[j] = (short)bf16rne(ph[j] * sc);
                wh[q][kt] = v;
            }
#pragma unroll
            for (int kt = 0; kt < 4; kt++) {
                short8 v = {0, 0, 0, 0, 0, 0, 0, 0};
                if (kt < KX) {
                    const float* px = Wih + (size_t)row * kin + kt * 32 + quad * 8;
#pragma unroll
                    for (int j = 0; j < 8; j++) v[j] = (short)bf16rne(px[j] * sc);
                }
                wx[q][kt] = v;
            }
        }
    }

    unsigned* myflag   = &flags[layer * 32 + grp];
    unsigned* prevflag = &flags[(layer > 0 ? layer - 1 : 0) * 32 + grp];
    unsigned* mycons   = &cons[(layer > 0 ? layer - 1 : 0) * 32 + grp];
    unsigned* nextcons = &cons[layer * 32 + grp];
    char* prodRing = ws + RING_OFF + (size_t)(layer * 32 + grp) * RING_BPG;
    char* consRing = ws + RING_OFF + (size_t)((layer > 0 ? layer - 1 : 0) * 32 + grp) * RING_BPG;

    // precomputed byte offsets
    const int ahrd  = col * 264 + quad * 16;                    // A-frag base
    const int hwr   = (quad * 4) * 264 + (wv * 16 + col) * 2;   // h write base
    const int xgOff = (tid >> 6) * 32768 + b0 * 64 + (tid & 63) * 16;   // xT chunk
    const int xlw0  = (tid >> 6) * 4224 + ((tid >> 2) & 15) * 264 + (tid & 3) * 16;
    // 16B export/stage mapping: thread covers 16B of a 4KB ring slot
    const int ehalf = tid >> 8;                        // slot parity (0/1)
    const int erow  = (tid & 255) >> 4;                // row within slot
    const int eLds  = erow * 264 + (tid & 15) * 16;    // LDS byte offset in a slot
    const int eRing = (tid & 255) * 16;                // ring byte offset in a slot

    intx4  xin4[4];
    short8 xv = {0, 0, 0, 0, 0, 0, 0, 0};
    unsigned pf = 0, pc = 0;
    float c4[4] = {0.f, 0.f, 0.f, 0.f};
    floatx4 accx[4];               // carried x-part partial sums for step t+1

    __syncthreads();                                   // LDS zeros visible

    // ---- prologue: load+stage chunks 0,1 (16 slots) ----------------------
    if (layer > 0) {
        if (tid == 0) { while (ald(prevflag) < 2u) {} }
        __syncthreads();
        intx4 pin[8];
#pragma unroll
        for (int p = 0; p < 8; p++) {
            int s = 2 * p + ehalf;                     // 0..15
            ld16_sc1_issue(consRing + (size_t)(s >> 3) * 32768 + (s & 7) * 4096 + eRing,
                           &pin[p]);
        }
        wait_vm0();
#pragma unroll
        for (int p = 0; p < 8; p++) {
            int s = 2 * p + ehalf;
            *(intx2*)(XlB + s * 4224 + eLds)     = pin[p].xy;
            *(intx2*)(XlB + s * 4224 + eLds + 8) = pin[p].zw;
        }
    } else {
#pragma unroll
        for (int c0 = 0; c0 < 2; c0++) {
            short8 v = *(const short8*)(xTB + (size_t)c0 * 262144 + xgOff);
            *(short8*)(XlB + xlw0 + c0 * 33792) = v;
        }
    }
    __syncthreads();

    // ---- prologue: accx for t=0 (x-part from Xl slot 0) ------------------
    {
        short8 ax0[4];
#pragma unroll
        for (int kt = 0; kt < 4; kt++)
            ax0[kt] = *(const short8*)(XlB + ahrd + 0 * 4224 + kt * 64);
#pragma unroll
        for (int q = 0; q < 4; q++) {
            floatx4 a = {bias_q[q], bias_q[q], bias_q[q], bias_q[q]};
            accx[q] = a;
        }
#pragma unroll
        for (int kt = 0; kt < 4; kt++)
#pragma unroll
            for (int q = 0; q < 4; q++)
                accx[q] = __builtin_amdgcn_mfma_f32_16x16x32_bf16(ax0[kt], wx[q][kt], accx[q], 0, 0, 0);
    }

    int c = 0;
    auto step = [&](auto UC) {
        constexpr int u   = UC.value;
        constexpr bool bnd = (u == 0 || u == 8);
        constexpr bool stg = (u == 3 || u == 11);
        constexpr bool ver = (u == 7 || u == 15);
        constexpr int sph = (u < 8) ? 8 : 0;           // slot base for export/stage
        const int cc = c + (u >> 3);
        if (bnd) {
            if (tid == 0) {
                if (layer > 0 && cc <= 111) pf = ald(prevflag);
                if (layer < 3 && cc >= 8)   pc = ald(nextcons);
            }
            // consumer: issue 4x16B ring loads for chunk cc+1 (no wait)
            if (layer > 0 && cc <= 112) {
                const char* rb2 = consRing + (size_t)((cc + 1) & 7) * 32768;
#pragma unroll
                for (int p = 0; p < 4; p++) {
                    int s = 2 * p + ehalf;
                    ld16_sc1_issue(rb2 + s * 4096 + eRing, &xin4[p]);
                }
            }
            // producer: burst chunk cc-1 (history slots sph..sph+7) -> ring
            if (layer < 3 && cc >= 1) {
                char* rb = prodRing + (size_t)((cc - 1) & 7) * 32768;
#pragma unroll
                for (int p = 0; p < 4; p++) {
                    int s = 2 * p + ehalf;
                    intx2 lo = *(const intx2*)(AhB + (sph + s) * 4224 + eLds);
                    intx2 hi = *(const intx2*)(AhB + (sph + s) * 4224 + eLds + 8);
                    intx4 v; v.xy = lo; v.zw = hi;
                    st16_sc1(rb + s * 4096 + eRing, v);
                }
            }
            if (layer == 0 && cc <= 112)
                xv = *(const short8*)(xTB + (size_t)(cc + 1) * 262144 + xgOff);
        }
        if (stg) {                                     // stage chunk cc+1 into Xl
            if (layer > 0) {
                wait_vm0_tied(&xin4[0], &xin4[1], &xin4[2], &xin4[3]);
#pragma unroll
                for (int p = 0; p < 4; p++) {
                    int s = sph + 2 * p + ehalf;
                    *(intx2*)(XlB + s * 4224 + eLds)     = xin4[p].xy;
                    *(intx2*)(XlB + s * 4224 + eLds + 8) = xin4[p].zw;
                }
            } else {
                *(short8*)(XlB + xlw0 + sph * 4224) = xv;
            }
        }
        // ---- A fragments: h(t-1) and x(t+1) ------------------------------
        short8 ah[4], axn[4];
#pragma unroll
        for (int kt = 0; kt < 4; kt++) {
            ah[kt]  = *(const short8*)(AhB + ahrd + ((u + 15) & 15) * 4224 + kt * 64);
            axn[kt] = *(const short8*)(XlB + ahrd + ((u + 1) & 15) * 4224 + kt * 64);
        }
        // ---- recurrent part: acc = accx + h(t-1)*Wh ----------------------
        floatx4 acc[4];
#pragma unroll
        for (int q = 0; q < 4; q++) acc[q] = accx[q];
#pragma unroll
        for (int kt = 0; kt < 4; kt++)
#pragma unroll
            for (int q = 0; q < 4; q++)
                acc[q] = __builtin_amdgcn_mfma_f32_16x16x32_bf16(ah[kt], wh[q][kt], acc[q], 0, 0, 0);
        // ---- gates(t) INTERLEAVED with x-MFMAs for t+1 --------------------
#pragma unroll
        for (int q = 0; q < 4; q++) {
            floatx4 a = {bias_q[q], bias_q[q], bias_q[q], bias_q[q]};
            accx[q] = a;
        }
#pragma unroll
        for (int r = 0; r < 4; r++) {
            float iv = fastsig(acc[0][r]);
            float fv = fastsig(acc[1][r]);
            float gr = fastsig(acc[2][r]);             // (tanh(g)+1)/2
            float ov = fastsig(acc[3][r]);
#pragma unroll
            for (int q = 0; q < 4; q++)
                accx[q] = __builtin_amdgcn_mfma_f32_16x16x32_bf16(axn[r], wx[q][r], accx[q], 0, 0, 0);
            float gt = 2.f * gr - 1.f;
            float cv = fv * c4[r] + iv * gt;
            c4[r] = cv;
            float rc = fastsig(-2.88539008f * cv);
            float hv = ov * (2.f * rc - 1.f);
            *(unsigned short*)(AhB + hwr + u * 4224 + r * 264) = bf16rne(hv);
        }
        if (stg) {
            wait_vm0();                                // ring stores acked at MALL
            __syncthreads();                           // release point
            if (tid == 0) {
                if (layer < 3 && cc >= 1) ast32(myflag, (unsigned)cc);
                if (layer > 0) ast32(mycons, (unsigned)(cc + 2));
            }
        } else {
            if (ver && tid == 0) {
                if (layer > 0 && cc <= 111) {
                    unsigned tgt = cc + 3;
                    if (pf < tgt) while (ald(prevflag) < tgt) {}
                }
                if (layer < 3 && cc >= 8) {
                    unsigned tgt = cc - 7;
                    if (pc < tgt) while (ald(nextcons) < tgt) {}
                }
            }
            bar_fast();
        }
    };

    for (c = 0; c < 114; c += 2) {
        step(IC<0>{});  step(IC<1>{});  step(IC<2>{});  step(IC<3>{});
        step(IC<4>{});  step(IC<5>{});  step(IC<6>{});  step(IC<7>{});
        step(IC<8>{});  step(IC<9>{});  step(IC<10>{}); step(IC<11>{});
        step(IC<12>{}); step(IC<13>{}); step(IC<14>{}); step(IC<15>{});
    }

    // ---- epilogue: burst chunk 113 (hist slots 8..15), publish, hN -------
    if (layer < 3) {
        char* rb = prodRing + (size_t)(113 & 7) * 32768;
#pragma unroll
        for (int p = 0; p < 4; p++) {
            int s = 2 * p + ehalf;
            intx2 lo = *(const intx2*)(AhB + (8 + s) * 4224 + eLds);
            intx2 hi = *(const intx2*)(AhB + (8 + s) * 4224 + eLds + 8);
            intx4 v; v.xy = lo; v.zw = hi;
            st16_sc1(rb + s * 4096 + eRing, v);
        }
        wait_vm0();
    }
    __syncthreads();
    if (tid == 0 && layer < 3) ast32(myflag, 114u);
    {   // export h[911] (hist slot 15) to hN
        intx2 lo = *(const intx2*)(AhB + 15 * 4224 + eLds);
        intx2 hi = *(const intx2*)(AhB + 15 * 4224 + eLds + 8);
        char* o = hN8 + ((size_t)layer * 512 + b0 + erow) * 256 + (tid & 15) * 16
                  + (size_t)ehalf * 0;                 // ehalf splits rows? no:
        // rows 0..15 covered by erow for each half; both halves write same rows
        // -> restrict to ehalf==0 half writing 16B chunks 0..15? Use full map:
        (void)o;
    }
    if (ehalf == 0) {
        intx2 lo = *(const intx2*)(AhB + 15 * 4224 + eLds);
        intx2 hi = *(const intx2*)(AhB + 15 * 4224 + eLds + 8);
        char* o = hN8 + ((size_t)layer * 512 + b0 + erow) * 256 + (tid & 15) * 16;
        *(intx2*)(o)     = lo;
        *(intx2*)(o + 8) = hi;
    }
}

// ---------------------------------------------------------------------------
// heads: hN [4][512][128] bf16 -> opt/tp/sl/lot, each [4][512][4] fp32
__global__ __launch_bounds__(256) void heads(
    const unsigned short* __restrict__ hN,
    const float* __restrict__ Wopt, const float* __restrict__ bopt,
    const float* __restrict__ Wlot, const float* __restrict__ blot,
    const float* __restrict__ Wtp,  const float* __restrict__ btp,
    const float* __restrict__ Wsl,  const float* __restrict__ bsl,
    float* __restrict__ out) {
    int tid = blockIdx.x * 256 + threadIdx.x;
    if (tid >= 4 * 4 * 512) return;
    int b  = tid & 511;
    int l  = (tid >> 9) & 3;
    int hd = tid >> 11;
    const float *W, *bb;
    if      (hd == 0) { W = Wopt; bb = bopt; }
    else if (hd == 1) { W = Wtp;  bb = btp;  }
    else if (hd == 2) { W = Wsl;  bb = bsl;  }
    else              { W = Wlot; bb = blot; }
    const unsigned short* h = hN + ((size_t)l * 512 + b) * 128;
    float z0 = bb[0], z1 = bb[1], z2 = bb[2], z3 = bb[3];
    for (int i = 0; i < 128; i++) {
        float hv = bf16tof(h[i]);
        z0 += hv * W[0 * 128 + i];
        z1 += hv * W[1 * 128 + i];
        z2 += hv * W[2 * 128 + i];
        z3 += hv * W[3 * 128 + i];
    }
    float o0, o1, o2, o3;
    if (hd == 0) {
        float m = fmaxf(fmaxf(z0, z1), fmaxf(z2, z3));
        float e0 = __builtin_amdgcn_exp2f((z0 - m) * 1.44269504f);
        float e1 = __builtin_amdgcn_exp2f((z1 - m) * 1.44269504f);
        float e2 = __builtin_amdgcn_exp2f((z2 - m) * 1.44269504f);
        float e3 = __builtin_amdgcn_exp2f((z3 - m) * 1.44269504f);
        float rs = __builtin_amdgcn_rcpf(e0 + e1 + e2 + e3);
        float p0 = e0 * rs, p1 = e1 * rs, p2 = e2 * rs, p3 = e3 * rs;
        float m2 = fmaxf(fmaxf(p0, p1), fmaxf(p2, p3));
        float f0 = __builtin_amdgcn_exp2f((p0 - m2) * 1.44269504f);
        float f1 = __builtin_amdgcn_exp2f((p1 - m2) * 1.44269504f);
        float f2 = __builtin_amdgcn_exp2f((p2 - m2) * 1.44269504f);
        float f3 = __builtin_amdgcn_exp2f((p3 - m2) * 1.44269504f);
        float rs2 = __builtin_amdgcn_rcpf(f0 + f1 + f2 + f3);
        o0 = f0 * rs2; o1 = f1 * rs2; o2 = f2 * rs2; o3 = f3 * rs2;
    } else {
        o0 = sigm(sigm(z0)); o1 = sigm(sigm(z1));
        o2 = sigm(sigm(z2)); o3 = sigm(sigm(z3));
    }
    float* o = out + (size_t)hd * 8192 + ((size_t)l * 512 + b) * 4;
    o[0] = o0; o[1] = o1; o[2] = o2; o[3] = o3;
}

// ---------------------------------------------------------------------------
extern "C" void kernel_launch(void* const* d_in, const int* in_sizes, int n_in,
                              void* d_out, int out_size, void* d_ws, size_t ws_size,
                              hipStream_t stream) {
    (void)in_sizes; (void)n_in; (void)out_size; (void)ws_size;
    const float* x      = (const float*)d_in[0];
    const float* Wih0   = (const float*)d_in[1];
    const float* Whh0   = (const float*)d_in[2];
    const float* bih0   = (const float*)d_in[3];
    const float* bhh0   = (const float*)d_in[4];
    const float* Wih123 = (const float*)d_in[5];
    const float* Whh123 = (const float*)d_in[6];
    const float* bih123 = (const float*)d_in[7];
    const float* bhh123 = (const float*)d_in[8];
    const float* Wopt = (const float*)d_in[9];
    const float* bopt = (const float*)d_in[10];
    const float* Wlot = (const float*)d_in[11];
    const float* blot = (const float*)d_in[12];
    const float* Wtp  = (const float*)d_in[13];
    const float* btp  = (const float*)d_in[14];
    const float* Wsl  = (const float*)d_in[15];
    const float* bsl  = (const float*)d_in[16];
    char* ws = (char*)d_ws;

    hipMemsetAsync(ws, 0, 1024, stream);               // flags + cons
    xpose<<<(B_ * T_ * 4 + 255) / 256, 256, 0, stream>>>(x, (unsigned short*)(ws + XT_OFF));
    lstm_scan<<<128, 512, 0, stream>>>(Wih0, Whh0, bih0, bhh0,
                                       Wih123, Whh123, bih123, bhh123, ws);
    heads<<<32, 256, 0, stream>>>((const unsigned short*)(ws + HN_OFF),
                                  Wopt, bopt, Wlot, blot, Wtp, btp, Wsl, bsl,
                                  (float*)d_out);
}